// Round 8
// baseline (226.164 us; speedup 1.0000x reference)
//
#include <hip/hip_runtime.h>
#include <hip/hip_bf16.h>

#define HW_N 9216
#define CH 256
#define KBLK 32
#define TILEB (KBLK * 512)               // 16384 B per LDS buffer (32 rows x 512 B)
#define SCALE2 144.269504089f            // 100 / ln(2), folded into xn at normalize time
#define INV_SCALE2 6.93147180559945e-3f  // ln(2) / 100

typedef __attribute__((ext_vector_type(8))) short bf16x8;
typedef __attribute__((ext_vector_type(4))) float f32x4;

__device__ inline unsigned short f2b(float f) {
    unsigned u = __builtin_bit_cast(unsigned, f);
    u += 0x7FFF + ((u >> 16) & 1);       // round-to-nearest-even
    return (unsigned short)(u >> 16);
}

// async global -> LDS, 16 B per lane; LDS dest is wave-uniform base + lane*16
__device__ inline void load_lds16(const void* g, void* l) {
    __builtin_amdgcn_global_load_lds(
        (const __attribute__((address_space(1))) unsigned*)g,
        (__attribute__((address_space(3))) unsigned*)l, 16, 0, 0);
}

// ---------------- kernel 1: per-channel partial sums (deterministic) ---------------
__global__ void stats_partial(const float* __restrict__ x,
                              const float* __restrict__ y,
                              float* __restrict__ part) {
    int c = threadIdx.x;                  // 256 threads = 256 channels
    int r0 = blockIdx.x * 128;            // 72 blocks * 128 rows = 9216
    float xs = 0.f, xq = 0.f, ys = 0.f, yq = 0.f;
    for (int r = r0; r < r0 + 128; ++r) {
        float xv = x[(size_t)r * CH + c]; xs += xv; xq += xv * xv;
        float yv = y[(size_t)r * CH + c]; ys += yv; yq += yv * yv;
    }
    float* p = part + (size_t)blockIdx.x * 1024;
    p[c] = xs; p[256 + c] = xq; p[512 + c] = ys; p[768 + c] = yq;
}

// ---------------- kernel 2: finalize stats (x-side invnorm pre-scaled) -------------
__global__ void stats_final(const float* __restrict__ part, float* __restrict__ stats) {
    int c = threadIdx.x;
    float xs = 0.f, xq = 0.f, ys = 0.f, yq = 0.f;
    for (int b = 0; b < 72; ++b) {
        const float* p = part + (size_t)b * 1024;
        xs += p[c]; xq += p[256 + c]; ys += p[512 + c]; yq += p[768 + c];
    }
    stats[c]       = xs / (float)HW_N;
    stats[256 + c] = SCALE2 / sqrtf(xq);  // fold logit scale into xn
    stats[512 + c] = ys / (float)HW_N;
    stats[768 + c] = 1.0f / sqrtf(yq);
}

// ---------------- kernel 3: normalize f32 -> bf16 ---------------------------------
__global__ void normalize_k(const float* __restrict__ x,
                            const float* __restrict__ y,
                            const float* __restrict__ stats,
                            unsigned short* __restrict__ xn,
                            unsigned short* __restrict__ yn) {
    const float* src = blockIdx.y ? y : x;
    unsigned short* dst = blockIdx.y ? yn : xn;
    const float* st = stats + blockIdx.y * 512;
    int idx = (blockIdx.x * 256 + threadIdx.x) * 8;   // grid.x = 1152
    int c = idx & (CH - 1);
    float4 v0 = *(const float4*)(src + idx);
    float4 v1 = *(const float4*)(src + idx + 4);
    float f[8] = {v0.x, v0.y, v0.z, v0.w, v1.x, v1.y, v1.z, v1.w};
    bf16x8 o;
#pragma unroll
    for (int j = 0; j < 8; ++j)
        o[j] = (short)f2b((f[j] - st[c + j]) * st[256 + c + j]);
    *(bf16x8*)(dst + idx) = o;
}

// ---------------- kernel 4: fused corr -> softmax -> PV, 2-phase pipelined ---------
// 72*nsplit blocks (XCD-chunked swizzle), 256 thr = 4 waves, wave owns 32 q-rows.
// LDS: 2 x 16KB key tiles (32 keys each).
// NO __launch_bounds__: (256,2) was observed to pin residency at ~2 wg/CU
// (R3-R7 occupancy table); default metadata lets HW pack min(LDS:5, VGPR:4) = 4 wg/CU.
__global__ void attn_k(const unsigned short* __restrict__ xn,
                       const unsigned short* __restrict__ yn,
                       const float* __restrict__ refimg,
                       float* __restrict__ part, int nsplit) {
    __shared__ __attribute__((aligned(16))) char kt[2 * TILEB];
    int tid = threadIdx.x;
    int lane = tid & 63, wave = tid >> 6;
    int l15 = lane & 15, l16 = lane >> 4;

    // XCD-chunked bijective swizzle (grid % 8 == 0)
    int chunk = gridDim.x >> 3;
    int wg = (blockIdx.x & 7) * chunk + (blockIdx.x >> 3);
    int bx = wg % 72, by = wg / 72;
    int qb = bx * 128 + wave * 32;
    int keys_per_split = HW_N / nsplit;
    int key0 = by * keys_per_split;
    int ntile = keys_per_split / KBLK;

    // A fragments (xn pre-scaled by SCALE2): q = qb + qs*16 + l15, k = kk*32 + l16*8 + j
    bf16x8 a[2][8];
#pragma unroll
    for (int qs = 0; qs < 2; ++qs) {
        const unsigned short* xrow = xn + (size_t)(qb + qs * 16 + l15) * CH + l16 * 8;
#pragma unroll
        for (int kk = 0; kk < 8; ++kk) a[qs][kk] = *(const bf16x8*)(xrow + kk * 32);
    }

    // staging lane constants: call j covers rows 2*call + (lane>>5), 16B per lane
    int srow = lane >> 5;                  // 0/1
    int scol = (lane & 31) * 16;           // byte col within 512B row
    const char* ynb = (const char*)yn;

    // read-side lane constants: row = ct*16 + l15 -> xor mask (l15&7)<<4
    int xm = (l15 & 7) << 4;
    int rowb = l15 << 9;                   // l15 * 512
    int colp[8];
#pragma unroll
    for (int kk = 0; kk < 8; ++kk) colp[kk] = (kk * 64 + l16 * 16) ^ xm;

#define STAGE(bufoff, kb_) do {                                                        \
    _Pragma("unroll")                                                                  \
    for (int j = 0; j < 4; ++j) {                                                      \
        int call = wave * 4 + j;                                                       \
        int rr = call * 2 + srow;                                                      \
        const char* src_ = ynb + ((size_t)((kb_) + rr) << 9) + (scol ^ ((rr & 7) << 4)); \
        load_lds16(src_, kt + (bufoff) + call * 1024);                                 \
    }                                                                                  \
} while (0)

    // lane-local state: plain max + raw exp sums (logits bounded, no rescale needed)
    float M[2][4], den[2][4], nA[2][4], nB[2][4];
#pragma unroll
    for (int qs = 0; qs < 2; ++qs)
#pragma unroll
        for (int i = 0; i < 4; ++i) {
            M[qs][i] = -1e30f; den[qs][i] = 0.f; nA[qs][i] = 0.f; nB[qs][i] = 0.f;
        }

    const float* refA = refimg + HW_N;
    const float* refB = refimg + 2 * HW_N;

    int cur = 0;
    STAGE(0, key0);                                   // prologue: stage tile 0
    asm volatile("s_waitcnt vmcnt(0)" ::: "memory");
    __syncthreads();

    for (int t = 0; t < ntile; ++t) {
        int kb = key0 + t * KBLK;
        if (t + 1 < ntile) STAGE(cur ^ TILEB, kb + KBLK);   // async prefetch next tile

        const char* ktc = kt + cur;
        f32x4 acc0[2], acc1[2];
#pragma unroll
        for (int ct = 0; ct < 2; ++ct) {
            acc0[ct] = (f32x4){0.f, 0.f, 0.f, 0.f};
            acc1[ct] = (f32x4){0.f, 0.f, 0.f, 0.f};
        }
        // kk outer, ct inner: 4 independent acc chains
#pragma unroll
        for (int kk = 0; kk < 8; ++kk) {
            bf16x8 b0 = *(const bf16x8*)(ktc + 0 * 8192 + rowb + colp[kk]);
            bf16x8 b1 = *(const bf16x8*)(ktc + 1 * 8192 + rowb + colp[kk]);
            acc0[0] = __builtin_amdgcn_mfma_f32_16x16x32_bf16(a[0][kk], b0, acc0[0], 0, 0, 0);
            acc1[0] = __builtin_amdgcn_mfma_f32_16x16x32_bf16(a[1][kk], b0, acc1[0], 0, 0, 0);
            acc0[1] = __builtin_amdgcn_mfma_f32_16x16x32_bf16(a[0][kk], b1, acc0[1], 0, 0, 0);
            acc1[1] = __builtin_amdgcn_mfma_f32_16x16x32_bf16(a[1][kk], b1, acc1[1], 0, 0, 0);
        }
        float va[2], vb[2];
#pragma unroll
        for (int ct = 0; ct < 2; ++ct) {
            int key = kb + ct * 16 + l15;
            va[ct] = refA[key]; vb[ct] = refB[key];
        }
        // acc[ct][i] = scaled corr[q = qb + qs*16 + l16*4 + i][key = kb + ct*16 + l15]
#pragma unroll
        for (int qs = 0; qs < 2; ++qs)
#pragma unroll
            for (int i = 0; i < 4; ++i) {
                float c0 = qs ? acc1[0][i] : acc0[0][i];
                float c1 = qs ? acc1[1][i] : acc0[1][i];
                M[qs][i] = fmaxf(M[qs][i], fmaxf(c0, c1));
                float p0 = exp2f(c0);
                float p1 = exp2f(c1);
                den[qs][i] += p0 + p1;
                nA[qs][i] += p0 * va[0] + p1 * va[1];
                nB[qs][i] += p0 * vb[0] + p1 * vb[1];
            }

        asm volatile("s_waitcnt vmcnt(0)" ::: "memory");  // next-tile stage landed
        __syncthreads();                                   // publish to all waves
        cur ^= TILEB;
    }

    // merge lane-local states across the 16 column-lanes: plain sum + max
#pragma unroll
    for (int qs = 0; qs < 2; ++qs)
#pragma unroll
        for (int i = 0; i < 4; ++i) {
#pragma unroll
            for (int off = 1; off < 16; off <<= 1) {
                M[qs][i]   = fmaxf(M[qs][i], __shfl_xor(M[qs][i], off, 64));
                den[qs][i] += __shfl_xor(den[qs][i], off, 64);
                nA[qs][i]  += __shfl_xor(nA[qs][i], off, 64);
                nB[qs][i]  += __shfl_xor(nB[qs][i], off, 64);
            }
        }
    if (l15 == 0) {
#pragma unroll
        for (int qs = 0; qs < 2; ++qs)
#pragma unroll
            for (int i = 0; i < 4; ++i) {
                int q = qb + qs * 16 + l16 * 4 + i;
                float* p = part + ((size_t)by * HW_N + q) * 4;
                p[0] = M[qs][i]; p[1] = den[qs][i]; p[2] = nA[qs][i]; p[3] = nB[qs][i];
            }
    }
#undef STAGE
}

// ---------------- kernel 5: merge splits, write f32 outputs ------------------------
__global__ void combine_k(const float* __restrict__ part, float* __restrict__ out,
                          int nsplit) {
    int q = blockIdx.x * 256 + threadIdx.x;           // 36 blocks
    float M = -1e30f, den = 0.f, nA = 0.f, nB = 0.f;
    for (int s = 0; s < nsplit; ++s) {
        const float* p = part + ((size_t)s * HW_N + q) * 4;
        M = fmaxf(M, p[0]); den += p[1]; nA += p[2]; nB += p[3];
    }
    out[q]            = nA / den;            // W channel a
    out[HW_N + q]     = nB / den;            // W channel b
    out[2 * HW_N + q] = M * INV_SCALE2;      // confidence = max corr (unscale)
}

extern "C" void kernel_launch(void* const* d_in, const int* in_sizes, int n_in,
                              void* d_out, int out_size, void* d_ws, size_t ws_size,
                              hipStream_t stream) {
    (void)in_sizes; (void)n_in; (void)out_size;
    const float* x   = (const float*)d_in[0];
    const float* y   = (const float*)d_in[1];
    const float* ref = (const float*)d_in[2];
    float* out = (float*)d_out;

    char* ws = (char*)d_ws;
    unsigned short* xn = (unsigned short*)ws;                     // 4718592 B
    unsigned short* yn = (unsigned short*)(ws + 4718592);         // 4718592 B
    float* partA = (float*)ws;                                    // 294912 B (dead before xn written)
    float* stats = (float*)(ws + 2 * 4718592);                    // 4096 B
    float* partS = (float*)(ws + 2 * 4718592 + 4096);             // nsplit*9216*16 B

    // choose key-split count from available workspace (deterministic: ws_size fixed)
    size_t base = 2 * 4718592 + 4096;
    int nsplit = (ws_size >= base + (size_t)12 * HW_N * 16) ? 12 : 6;

    hipLaunchKernelGGL(stats_partial, dim3(72), dim3(256), 0, stream, x, y, partA);
    hipLaunchKernelGGL(stats_final, dim3(1), dim3(256), 0, stream, partA, stats);
    hipLaunchKernelGGL(normalize_k, dim3(1152, 2), dim3(256), 0, stream, x, y, stats, xn, yn);
    hipLaunchKernelGGL(attn_k, dim3(72 * nsplit), dim3(256), 0, stream, xn, yn, ref, partS, nsplit);
    hipLaunchKernelGGL(combine_k, dim3(36), dim3(256), 0, stream, partS, out, nsplit);
}

// Round 9
// 114.552 us; speedup vs baseline: 1.9743x; 1.9743x over previous
//
#include <hip/hip_runtime.h>
#include <hip/hip_bf16.h>

#define HW_N 9216
#define CH 256
#define KBLK 32
#define TILEB (KBLK * 512)               // 16384 B per LDS buffer (32 rows x 512 B)
#define SCALE2 144.269504089f            // 100 / ln(2), folded into xn at normalize time
#define INV_SCALE2 6.93147180559945e-3f  // ln(2) / 100

typedef __attribute__((ext_vector_type(8))) short bf16x8;
typedef __attribute__((ext_vector_type(4))) float f32x4;

__device__ inline unsigned short f2b(float f) {
    unsigned u = __builtin_bit_cast(unsigned, f);
    u += 0x7FFF + ((u >> 16) & 1);       // round-to-nearest-even
    return (unsigned short)(u >> 16);
}

// async global -> LDS, 16 B per lane; LDS dest is wave-uniform base + lane*16
__device__ inline void load_lds16(const void* g, void* l) {
    __builtin_amdgcn_global_load_lds(
        (const __attribute__((address_space(1))) unsigned*)g,
        (__attribute__((address_space(3))) unsigned*)l, 16, 0, 0);
}

// ---------------- kernel 1: per-channel partial sums (deterministic) ---------------
__global__ void stats_partial(const float* __restrict__ x,
                              const float* __restrict__ y,
                              float* __restrict__ part) {
    int c = threadIdx.x;                  // 256 threads = 256 channels
    int r0 = blockIdx.x * 128;            // 72 blocks * 128 rows = 9216
    float xs = 0.f, xq = 0.f, ys = 0.f, yq = 0.f;
    for (int r = r0; r < r0 + 128; ++r) {
        float xv = x[(size_t)r * CH + c]; xs += xv; xq += xv * xv;
        float yv = y[(size_t)r * CH + c]; ys += yv; yq += yv * yv;
    }
    float* p = part + (size_t)blockIdx.x * 1024;
    p[c] = xs; p[256 + c] = xq; p[512 + c] = ys; p[768 + c] = yq;
}

// ---------------- kernel 2: finalize stats (x-side invnorm pre-scaled) -------------
__global__ void stats_final(const float* __restrict__ part, float* __restrict__ stats) {
    int c = threadIdx.x;
    float xs = 0.f, xq = 0.f, ys = 0.f, yq = 0.f;
    for (int b = 0; b < 72; ++b) {
        const float* p = part + (size_t)b * 1024;
        xs += p[c]; xq += p[256 + c]; ys += p[512 + c]; yq += p[768 + c];
    }
    stats[c]       = xs / (float)HW_N;
    stats[256 + c] = SCALE2 / sqrtf(xq);  // fold logit scale into xn
    stats[512 + c] = ys / (float)HW_N;
    stats[768 + c] = 1.0f / sqrtf(yq);
}

// ---------------- kernel 3: normalize f32 -> bf16 ---------------------------------
__global__ void normalize_k(const float* __restrict__ x,
                            const float* __restrict__ y,
                            const float* __restrict__ stats,
                            unsigned short* __restrict__ xn,
                            unsigned short* __restrict__ yn) {
    const float* src = blockIdx.y ? y : x;
    unsigned short* dst = blockIdx.y ? yn : xn;
    const float* st = stats + blockIdx.y * 512;
    int idx = (blockIdx.x * 256 + threadIdx.x) * 8;   // grid.x = 1152
    int c = idx & (CH - 1);
    float4 v0 = *(const float4*)(src + idx);
    float4 v1 = *(const float4*)(src + idx + 4);
    float f[8] = {v0.x, v0.y, v0.z, v0.w, v1.x, v1.y, v1.z, v1.w};
    bf16x8 o;
#pragma unroll
    for (int j = 0; j < 8; ++j)
        o[j] = (short)f2b((f[j] - st[c + j]) * st[256 + c + j]);
    *(bf16x8*)(dst + idx) = o;
}

// ---------------- kernel 4: fused corr -> softmax -> PV, 2-phase pipelined ---------
// 72*nsplit blocks (XCD-chunked swizzle), 256 thr = 4 waves, wave owns 32 q-rows.
// LDS: 2 x 16KB key tiles (32 keys each).
// (256,3): occupancy target 3 wg/CU with VGPR cap ~170 -> same spill-free codegen
// as R7 (needs ~104), but HW packs 3 blocks/CU instead of 2.
// Evidence: (256,2) -> 16-18% occ; (256,4)/default -> 35% occ but VGPR forced to 64
// -> 195MB spill traffic (R4, R8). (256,3) targets the gap.
__launch_bounds__(256, 3)
__global__ void attn_k(const unsigned short* __restrict__ xn,
                       const unsigned short* __restrict__ yn,
                       const float* __restrict__ refimg,
                       float* __restrict__ part, int nsplit) {
    __shared__ __attribute__((aligned(16))) char kt[2 * TILEB];
    int tid = threadIdx.x;
    int lane = tid & 63, wave = tid >> 6;
    int l15 = lane & 15, l16 = lane >> 4;

    // XCD-chunked bijective swizzle (grid % 8 == 0)
    int chunk = gridDim.x >> 3;
    int wg = (blockIdx.x & 7) * chunk + (blockIdx.x >> 3);
    int bx = wg % 72, by = wg / 72;
    int qb = bx * 128 + wave * 32;
    int keys_per_split = HW_N / nsplit;
    int key0 = by * keys_per_split;
    int ntile = keys_per_split / KBLK;

    // A fragments (xn pre-scaled by SCALE2): q = qb + qs*16 + l15, k = kk*32 + l16*8 + j
    bf16x8 a[2][8];
#pragma unroll
    for (int qs = 0; qs < 2; ++qs) {
        const unsigned short* xrow = xn + (size_t)(qb + qs * 16 + l15) * CH + l16 * 8;
#pragma unroll
        for (int kk = 0; kk < 8; ++kk) a[qs][kk] = *(const bf16x8*)(xrow + kk * 32);
    }

    // staging lane constants: call j covers rows 2*call + (lane>>5), 16B per lane
    int srow = lane >> 5;                  // 0/1
    int scol = (lane & 31) * 16;           // byte col within 512B row
    const char* ynb = (const char*)yn;

    // read-side lane constants: row = ct*16 + l15 -> xor mask (l15&7)<<4
    int xm = (l15 & 7) << 4;
    int rowb = l15 << 9;                   // l15 * 512
    int colp[8];
#pragma unroll
    for (int kk = 0; kk < 8; ++kk) colp[kk] = (kk * 64 + l16 * 16) ^ xm;

#define STAGE(bufoff, kb_) do {                                                        \
    _Pragma("unroll")                                                                  \
    for (int j = 0; j < 4; ++j) {                                                      \
        int call = wave * 4 + j;                                                       \
        int rr = call * 2 + srow;                                                      \
        const char* src_ = ynb + ((size_t)((kb_) + rr) << 9) + (scol ^ ((rr & 7) << 4)); \
        load_lds16(src_, kt + (bufoff) + call * 1024);                                 \
    }                                                                                  \
} while (0)

    // lane-local state: plain max + raw exp sums (logits bounded, no rescale needed)
    float M[2][4], den[2][4], nA[2][4], nB[2][4];
#pragma unroll
    for (int qs = 0; qs < 2; ++qs)
#pragma unroll
        for (int i = 0; i < 4; ++i) {
            M[qs][i] = -1e30f; den[qs][i] = 0.f; nA[qs][i] = 0.f; nB[qs][i] = 0.f;
        }

    const float* refA = refimg + HW_N;
    const float* refB = refimg + 2 * HW_N;

    int cur = 0;
    STAGE(0, key0);                                   // prologue: stage tile 0
    asm volatile("s_waitcnt vmcnt(0)" ::: "memory");
    __syncthreads();

    for (int t = 0; t < ntile; ++t) {
        int kb = key0 + t * KBLK;
        if (t + 1 < ntile) STAGE(cur ^ TILEB, kb + KBLK);   // async prefetch next tile

        const char* ktc = kt + cur;
        f32x4 acc0[2], acc1[2];
#pragma unroll
        for (int ct = 0; ct < 2; ++ct) {
            acc0[ct] = (f32x4){0.f, 0.f, 0.f, 0.f};
            acc1[ct] = (f32x4){0.f, 0.f, 0.f, 0.f};
        }
        // kk outer, ct inner: 4 independent acc chains
#pragma unroll
        for (int kk = 0; kk < 8; ++kk) {
            bf16x8 b0 = *(const bf16x8*)(ktc + 0 * 8192 + rowb + colp[kk]);
            bf16x8 b1 = *(const bf16x8*)(ktc + 1 * 8192 + rowb + colp[kk]);
            acc0[0] = __builtin_amdgcn_mfma_f32_16x16x32_bf16(a[0][kk], b0, acc0[0], 0, 0, 0);
            acc1[0] = __builtin_amdgcn_mfma_f32_16x16x32_bf16(a[1][kk], b0, acc1[0], 0, 0, 0);
            acc0[1] = __builtin_amdgcn_mfma_f32_16x16x32_bf16(a[0][kk], b1, acc0[1], 0, 0, 0);
            acc1[1] = __builtin_amdgcn_mfma_f32_16x16x32_bf16(a[1][kk], b1, acc1[1], 0, 0, 0);
        }
        float va[2], vb[2];
#pragma unroll
        for (int ct = 0; ct < 2; ++ct) {
            int key = kb + ct * 16 + l15;
            va[ct] = refA[key]; vb[ct] = refB[key];
        }
        // acc[ct][i] = scaled corr[q = qb + qs*16 + l16*4 + i][key = kb + ct*16 + l15]
#pragma unroll
        for (int qs = 0; qs < 2; ++qs)
#pragma unroll
            for (int i = 0; i < 4; ++i) {
                float c0 = qs ? acc1[0][i] : acc0[0][i];
                float c1 = qs ? acc1[1][i] : acc0[1][i];
                M[qs][i] = fmaxf(M[qs][i], fmaxf(c0, c1));
                float p0 = exp2f(c0);
                float p1 = exp2f(c1);
                den[qs][i] += p0 + p1;
                nA[qs][i] += p0 * va[0] + p1 * va[1];
                nB[qs][i] += p0 * vb[0] + p1 * vb[1];
            }

        asm volatile("s_waitcnt vmcnt(0)" ::: "memory");  // next-tile stage landed
        __syncthreads();                                   // publish to all waves
        cur ^= TILEB;
    }

    // merge lane-local states across the 16 column-lanes: plain sum + max
#pragma unroll
    for (int qs = 0; qs < 2; ++qs)
#pragma unroll
        for (int i = 0; i < 4; ++i) {
#pragma unroll
            for (int off = 1; off < 16; off <<= 1) {
                M[qs][i]   = fmaxf(M[qs][i], __shfl_xor(M[qs][i], off, 64));
                den[qs][i] += __shfl_xor(den[qs][i], off, 64);
                nA[qs][i]  += __shfl_xor(nA[qs][i], off, 64);
                nB[qs][i]  += __shfl_xor(nB[qs][i], off, 64);
            }
        }
    if (l15 == 0) {
#pragma unroll
        for (int qs = 0; qs < 2; ++qs)
#pragma unroll
            for (int i = 0; i < 4; ++i) {
                int q = qb + qs * 16 + l16 * 4 + i;
                float* p = part + ((size_t)by * HW_N + q) * 4;
                p[0] = M[qs][i]; p[1] = den[qs][i]; p[2] = nA[qs][i]; p[3] = nB[qs][i];
            }
    }
#undef STAGE
}

// ---------------- kernel 5: merge splits, write f32 outputs ------------------------
__global__ void combine_k(const float* __restrict__ part, float* __restrict__ out,
                          int nsplit) {
    int q = blockIdx.x * 256 + threadIdx.x;           // 36 blocks
    float M = -1e30f, den = 0.f, nA = 0.f, nB = 0.f;
    for (int s = 0; s < nsplit; ++s) {
        const float* p = part + ((size_t)s * HW_N + q) * 4;
        M = fmaxf(M, p[0]); den += p[1]; nA += p[2]; nB += p[3];
    }
    out[q]            = nA / den;            // W channel a
    out[HW_N + q]     = nB / den;            // W channel b
    out[2 * HW_N + q] = M * INV_SCALE2;      // confidence = max corr (unscale)
}

extern "C" void kernel_launch(void* const* d_in, const int* in_sizes, int n_in,
                              void* d_out, int out_size, void* d_ws, size_t ws_size,
                              hipStream_t stream) {
    (void)in_sizes; (void)n_in; (void)out_size;
    const float* x   = (const float*)d_in[0];
    const float* y   = (const float*)d_in[1];
    const float* ref = (const float*)d_in[2];
    float* out = (float*)d_out;

    char* ws = (char*)d_ws;
    unsigned short* xn = (unsigned short*)ws;                     // 4718592 B
    unsigned short* yn = (unsigned short*)(ws + 4718592);         // 4718592 B
    float* partA = (float*)ws;                                    // 294912 B (dead before xn written)
    float* stats = (float*)(ws + 2 * 4718592);                    // 4096 B
    float* partS = (float*)(ws + 2 * 4718592 + 4096);             // nsplit*9216*16 B

    // choose key-split count from available workspace (deterministic: ws_size fixed)
    size_t base = 2 * 4718592 + 4096;
    int nsplit = (ws_size >= base + (size_t)12 * HW_N * 16) ? 12 : 6;

    hipLaunchKernelGGL(stats_partial, dim3(72), dim3(256), 0, stream, x, y, partA);
    hipLaunchKernelGGL(stats_final, dim3(1), dim3(256), 0, stream, partA, stats);
    hipLaunchKernelGGL(normalize_k, dim3(1152, 2), dim3(256), 0, stream, x, y, stats, xn, yn);
    hipLaunchKernelGGL(attn_k, dim3(72 * nsplit), dim3(256), 0, stream, xn, yn, ref, partS, nsplit);
    hipLaunchKernelGGL(combine_k, dim3(36), dim3(256), 0, stream, partS, out, nsplit);
}

// Round 10
// 103.256 us; speedup vs baseline: 2.1903x; 1.1094x over previous
//
#include <hip/hip_runtime.h>
#include <hip/hip_bf16.h>

#define HW_N 9216
#define CH 256
#define KBLK 32
#define BUFSTRIDE 16640                  // 16384 B keys + 256 B colors per buffer
#define SCALE2 144.269504089f            // 100 / ln(2), folded into xn at normalize time
#define INV_SCALE2 6.93147180559945e-3f  // ln(2) / 100

typedef __attribute__((ext_vector_type(8))) short bf16x8;
typedef __attribute__((ext_vector_type(4))) float f32x4;

__device__ inline unsigned short f2b(float f) {
    unsigned u = __builtin_bit_cast(unsigned, f);
    u += 0x7FFF + ((u >> 16) & 1);       // round-to-nearest-even
    return (unsigned short)(u >> 16);
}

// async global -> LDS, 16 B per active lane; LDS dest = wave-uniform base + lane*16
__device__ inline void load_lds16(const void* g, void* l) {
    __builtin_amdgcn_global_load_lds(
        (const __attribute__((address_space(1))) unsigned*)g,
        (__attribute__((address_space(3))) unsigned*)l, 16, 0, 0);
}

// ---------------- kernel 1: per-channel partial sums (deterministic) ---------------
__global__ void stats_partial(const float* __restrict__ x,
                              const float* __restrict__ y,
                              float* __restrict__ part) {
    int c = threadIdx.x;                  // 256 threads = 256 channels
    int r0 = blockIdx.x * 128;            // 72 blocks * 128 rows = 9216
    float xs = 0.f, xq = 0.f, ys = 0.f, yq = 0.f;
    for (int r = r0; r < r0 + 128; ++r) {
        float xv = x[(size_t)r * CH + c]; xs += xv; xq += xv * xv;
        float yv = y[(size_t)r * CH + c]; ys += yv; yq += yv * yv;
    }
    float* p = part + (size_t)blockIdx.x * 1024;
    p[c] = xs; p[256 + c] = xq; p[512 + c] = ys; p[768 + c] = yq;
}

// ---------------- kernel 2: finalize stats (x-side invnorm pre-scaled) -------------
__global__ void stats_final(const float* __restrict__ part, float* __restrict__ stats) {
    int c = threadIdx.x;
    float xs = 0.f, xq = 0.f, ys = 0.f, yq = 0.f;
    for (int b = 0; b < 72; ++b) {
        const float* p = part + (size_t)b * 1024;
        xs += p[c]; xq += p[256 + c]; ys += p[512 + c]; yq += p[768 + c];
    }
    stats[c]       = xs / (float)HW_N;
    stats[256 + c] = SCALE2 / sqrtf(xq);  // fold logit scale into xn
    stats[512 + c] = ys / (float)HW_N;
    stats[768 + c] = 1.0f / sqrtf(yq);
}

// ---------------- kernel 3: normalize f32 -> bf16 ---------------------------------
__global__ void normalize_k(const float* __restrict__ x,
                            const float* __restrict__ y,
                            const float* __restrict__ stats,
                            unsigned short* __restrict__ xn,
                            unsigned short* __restrict__ yn) {
    const float* src = blockIdx.y ? y : x;
    unsigned short* dst = blockIdx.y ? yn : xn;
    const float* st = stats + blockIdx.y * 512;
    int idx = (blockIdx.x * 256 + threadIdx.x) * 8;   // grid.x = 1152
    int c = idx & (CH - 1);
    float4 v0 = *(const float4*)(src + idx);
    float4 v1 = *(const float4*)(src + idx + 4);
    float f[8] = {v0.x, v0.y, v0.z, v0.w, v1.x, v1.y, v1.z, v1.w};
    bf16x8 o;
#pragma unroll
    for (int j = 0; j < 8; ++j)
        o[j] = (short)f2b((f[j] - st[c + j]) * st[256 + c + j]);
    *(bf16x8*)(dst + idx) = o;
}

// ---------------- kernel 4: fused corr -> softmax -> PV, depth-2 counted-vmcnt -----
// 72*nsplit blocks (XCD swizzle), 256 thr = 4 waves, wave owns 32 q-rows.
// 4 LDS buffers; stage tile t+2 while computing t; end-of-tile waits vmcnt(5)
// (drains t+1's 5 loads, leaves t+2's 5 in flight) - never 0 in steady state.
// Colors (refA/refB) are staged into LDS with the tile so stage loads are the
// ONLY vmem ops in the loop -> the counted wait is exact (5 loads/wave/stage).
__launch_bounds__(256, 2)   // proven spill-free regime (R7: 104 VGPR, clean WRITE_SIZE)
__global__ void attn_k(const unsigned short* __restrict__ xn,
                       const unsigned short* __restrict__ yn,
                       const float* __restrict__ refimg,
                       float* __restrict__ part, int nsplit) {
    __shared__ __attribute__((aligned(16))) char kt[4 * BUFSTRIDE];  // 66560 B
    int tid = threadIdx.x;
    int lane = tid & 63, wave = tid >> 6;
    int l15 = lane & 15, l16 = lane >> 4;

    // XCD-chunked bijective swizzle (grid % 8 == 0)
    int chunk = gridDim.x >> 3;
    int wg = (blockIdx.x & 7) * chunk + (blockIdx.x >> 3);
    int bx = wg % 72, by = wg / 72;
    int qb = bx * 128 + wave * 32;
    int keys_per_split = HW_N / nsplit;
    int key0 = by * keys_per_split;
    int ntile = keys_per_split / KBLK;     // 24 (nsplit=12) or 48 (nsplit=6)

    // A fragments (xn pre-scaled by SCALE2): q = qb + qs*16 + l15, k = kk*32 + l16*8 + j
    bf16x8 a[2][8];
#pragma unroll
    for (int qs = 0; qs < 2; ++qs) {
        const unsigned short* xrow = xn + (size_t)(qb + qs * 16 + l15) * CH + l16 * 8;
#pragma unroll
        for (int kk = 0; kk < 8; ++kk) a[qs][kk] = *(const bf16x8*)(xrow + kk * 32);
    }

    // staging lane constants: key rows - call j covers rows 2*call + (lane>>5)
    int srow = lane >> 5;                  // 0/1
    int scol = (lane & 31) * 16;           // byte col within 512B row
    const char* ynb = (const char*)yn;
    // color staging: wave 0/1 -> refA halves, wave 2/3 -> refB halves; lanes 0-3 x 16B
    const char* cbase = (wave < 2) ? (const char*)(refimg + HW_N)
                                   : (const char*)(refimg + 2 * HW_N);
    int cwoff = (wave & 1) * 64;           // byte offset within the 128B color row

    // read-side: row = ct*16 + l15 -> xor mask (l15&7)<<4
    int xm = (l15 & 7) << 4;
    int rowb = l15 << 9;                   // l15 * 512
    int colp[8];
#pragma unroll
    for (int kk = 0; kk < 8; ++kk) colp[kk] = (kk * 64 + l16 * 16) ^ xm;

#define STAGE(bi, kb_) do {                                                              \
    char* dst_ = kt + (bi) * BUFSTRIDE;                                                  \
    _Pragma("unroll")                                                                    \
    for (int j = 0; j < 4; ++j) {                                                        \
        int call = wave * 4 + j;                                                         \
        int rr = call * 2 + srow;                                                        \
        const char* s_ = ynb + ((size_t)((kb_) + rr) << 9) + (scol ^ ((rr & 7) << 4));   \
        load_lds16(s_, dst_ + call * 1024);                                              \
    }                                                                                    \
    if (lane < 4)                                                                        \
        load_lds16(cbase + (size_t)(kb_) * 4 + cwoff + lane * 16,                        \
                   dst_ + 16384 + (wave >> 1) * 128 + cwoff);                            \
} while (0)

    // lane-local state: plain max + raw exp sums (logits bounded, no rescale needed)
    float M[2][4], den[2][4], nA[2][4], nB[2][4];
#pragma unroll
    for (int qs = 0; qs < 2; ++qs)
#pragma unroll
        for (int i = 0; i < 4; ++i) {
            M[qs][i] = -1e30f; den[qs][i] = 0.f; nA[qs][i] = 0.f; nB[qs][i] = 0.f;
        }

    STAGE(0, key0);                        // prologue: tiles 0 and 1 in flight
    STAGE(1, key0 + KBLK);
    asm volatile("s_waitcnt vmcnt(5)" ::: "memory");   // tile 0 landed (also drains A-frags)
    __syncthreads();

    for (int t = 0; t < ntile; ++t) {
        int kb = key0 + t * KBLK;
        if (t + 2 < ntile) STAGE((t + 2) & 3, kb + 2 * KBLK);   // depth-2 prefetch

        const char* ktc = kt + (t & 3) * BUFSTRIDE;
        f32x4 acc0[2], acc1[2];
#pragma unroll
        for (int ct = 0; ct < 2; ++ct) {
            acc0[ct] = (f32x4){0.f, 0.f, 0.f, 0.f};
            acc1[ct] = (f32x4){0.f, 0.f, 0.f, 0.f};
        }
        __builtin_amdgcn_s_setprio(1);
#pragma unroll
        for (int kk = 0; kk < 8; ++kk) {
            bf16x8 b0 = *(const bf16x8*)(ktc + 0 * 8192 + rowb + colp[kk]);
            bf16x8 b1 = *(const bf16x8*)(ktc + 1 * 8192 + rowb + colp[kk]);
            acc0[0] = __builtin_amdgcn_mfma_f32_16x16x32_bf16(a[0][kk], b0, acc0[0], 0, 0, 0);
            acc1[0] = __builtin_amdgcn_mfma_f32_16x16x32_bf16(a[1][kk], b0, acc1[0], 0, 0, 0);
            acc0[1] = __builtin_amdgcn_mfma_f32_16x16x32_bf16(a[0][kk], b1, acc0[1], 0, 0, 0);
            acc1[1] = __builtin_amdgcn_mfma_f32_16x16x32_bf16(a[1][kk], b1, acc1[1], 0, 0, 0);
        }
        __builtin_amdgcn_s_setprio(0);

        // colors from LDS (keeps vmem queue = stage loads only)
        const float* cols = (const float*)(ktc + 16384);
        float va[2], vb[2];
#pragma unroll
        for (int ct = 0; ct < 2; ++ct) {
            va[ct] = cols[ct * 16 + l15];
            vb[ct] = cols[32 + ct * 16 + l15];
        }
        // acc[ct][i] = scaled corr[q = qb + qs*16 + l16*4 + i][key = kb + ct*16 + l15]
#pragma unroll
        for (int qs = 0; qs < 2; ++qs)
#pragma unroll
            for (int i = 0; i < 4; ++i) {
                float c0 = qs ? acc1[0][i] : acc0[0][i];
                float c1 = qs ? acc1[1][i] : acc0[1][i];
                M[qs][i] = fmaxf(M[qs][i], fmaxf(c0, c1));
                float p0 = exp2f(c0);
                float p1 = exp2f(c1);
                den[qs][i] += p0 + p1;
                nA[qs][i] += p0 * va[0] + p1 * va[1];
                nB[qs][i] += p0 * vb[0] + p1 * vb[1];
            }

        // counted wait: drain tile t+1's 5 loads, keep tile t+2's 5 in flight
        if (t + 2 < ntile) {
            asm volatile("s_waitcnt vmcnt(5)" ::: "memory");
        } else if (t + 1 < ntile) {
            asm volatile("s_waitcnt vmcnt(0)" ::: "memory");
        }
        __syncthreads();
    }

    // merge lane-local states across the 16 column-lanes: plain sum + max
#pragma unroll
    for (int qs = 0; qs < 2; ++qs)
#pragma unroll
        for (int i = 0; i < 4; ++i) {
#pragma unroll
            for (int off = 1; off < 16; off <<= 1) {
                M[qs][i]   = fmaxf(M[qs][i], __shfl_xor(M[qs][i], off, 64));
                den[qs][i] += __shfl_xor(den[qs][i], off, 64);
                nA[qs][i]  += __shfl_xor(nA[qs][i], off, 64);
                nB[qs][i]  += __shfl_xor(nB[qs][i], off, 64);
            }
        }
    if (l15 == 0) {
#pragma unroll
        for (int qs = 0; qs < 2; ++qs)
#pragma unroll
            for (int i = 0; i < 4; ++i) {
                int q = qb + qs * 16 + l16 * 4 + i;
                float* p = part + ((size_t)by * HW_N + q) * 4;
                p[0] = M[qs][i]; p[1] = den[qs][i]; p[2] = nA[qs][i]; p[3] = nB[qs][i];
            }
    }
#undef STAGE
}

// ---------------- kernel 5: merge splits, write f32 outputs ------------------------
__global__ void combine_k(const float* __restrict__ part, float* __restrict__ out,
                          int nsplit) {
    int q = blockIdx.x * 256 + threadIdx.x;           // 36 blocks
    float M = -1e30f, den = 0.f, nA = 0.f, nB = 0.f;
    for (int s = 0; s < nsplit; ++s) {
        const float* p = part + ((size_t)s * HW_N + q) * 4;
        M = fmaxf(M, p[0]); den += p[1]; nA += p[2]; nB += p[3];
    }
    out[q]            = nA / den;            // W channel a
    out[HW_N + q]     = nB / den;            // W channel b
    out[2 * HW_N + q] = M * INV_SCALE2;      // confidence = max corr (unscale)
}

extern "C" void kernel_launch(void* const* d_in, const int* in_sizes, int n_in,
                              void* d_out, int out_size, void* d_ws, size_t ws_size,
                              hipStream_t stream) {
    (void)in_sizes; (void)n_in; (void)out_size;
    const float* x   = (const float*)d_in[0];
    const float* y   = (const float*)d_in[1];
    const float* ref = (const float*)d_in[2];
    float* out = (float*)d_out;

    char* ws = (char*)d_ws;
    unsigned short* xn = (unsigned short*)ws;                     // 4718592 B
    unsigned short* yn = (unsigned short*)(ws + 4718592);         // 4718592 B
    float* partA = (float*)ws;                                    // 294912 B (dead before xn written)
    float* stats = (float*)(ws + 2 * 4718592);                    // 4096 B
    float* partS = (float*)(ws + 2 * 4718592 + 4096);             // nsplit*9216*16 B

    // choose key-split count from available workspace (deterministic: ws_size fixed)
    size_t base = 2 * 4718592 + 4096;
    int nsplit = (ws_size >= base + (size_t)12 * HW_N * 16) ? 12 : 6;

    hipLaunchKernelGGL(stats_partial, dim3(72), dim3(256), 0, stream, x, y, partA);
    hipLaunchKernelGGL(stats_final, dim3(1), dim3(256), 0, stream, partA, stats);
    hipLaunchKernelGGL(normalize_k, dim3(1152, 2), dim3(256), 0, stream, x, y, stats, xn, yn);
    hipLaunchKernelGGL(attn_k, dim3(72 * nsplit), dim3(256), 0, stream, xn, yn, ref, partS, nsplit);
    hipLaunchKernelGGL(combine_k, dim3(36), dim3(256), 0, stream, partS, out, nsplit);
}

// Round 11
// 99.706 us; speedup vs baseline: 2.2683x; 1.0356x over previous
//
#include <hip/hip_runtime.h>
#include <hip/hip_bf16.h>

#define HW_N 9216
#define CH 256
#define KBLK 32                          // keys per loop iteration (2 keyblocks of 16)
#define SCALE2 144.269504089f            // 100 / ln(2), folded into xn at normalize time
#define INV_SCALE2 6.93147180559945e-3f  // ln(2) / 100

typedef __attribute__((ext_vector_type(8))) short bf16x8;
typedef __attribute__((ext_vector_type(4))) float f32x4;

__device__ inline unsigned short f2b(float f) {
    unsigned u = __builtin_bit_cast(unsigned, f);
    u += 0x7FFF + ((u >> 16) & 1);       // round-to-nearest-even
    return (unsigned short)(u >> 16);
}

// ---------------- kernel 1: per-channel partial sums (deterministic) ---------------
__global__ void stats_partial(const float* __restrict__ x,
                              const float* __restrict__ y,
                              float* __restrict__ part) {
    int c = threadIdx.x;                  // 256 threads = 256 channels
    int r0 = blockIdx.x * 128;            // 72 blocks * 128 rows = 9216
    float xs = 0.f, xq = 0.f, ys = 0.f, yq = 0.f;
    for (int r = r0; r < r0 + 128; ++r) {
        float xv = x[(size_t)r * CH + c]; xs += xv; xq += xv * xv;
        float yv = y[(size_t)r * CH + c]; ys += yv; yq += yv * yv;
    }
    float* p = part + (size_t)blockIdx.x * 1024;
    p[c] = xs; p[256 + c] = xq; p[512 + c] = ys; p[768 + c] = yq;
}

// ---------------- kernel 2: finalize stats (x-side invnorm pre-scaled) -------------
__global__ void stats_final(const float* __restrict__ part, float* __restrict__ stats) {
    int c = threadIdx.x;
    float xs = 0.f, xq = 0.f, ys = 0.f, yq = 0.f;
    for (int b = 0; b < 72; ++b) {
        const float* p = part + (size_t)b * 1024;
        xs += p[c]; xq += p[256 + c]; ys += p[512 + c]; yq += p[768 + c];
    }
    stats[c]       = xs / (float)HW_N;
    stats[256 + c] = SCALE2 / sqrtf(xq);  // fold logit scale into xn
    stats[512 + c] = ys / (float)HW_N;
    stats[768 + c] = 1.0f / sqrtf(yq);
}

// ---------------- kernel 3: normalize f32 -> bf16; y goes to PACKED layout ---------
// ynP element index: keyblk*4096 + kk*512 + l16*128 + l15*8 + j
//   (keyblk = key>>4, l15 = key&15, kk = ch>>5, l16 = (ch&31)>>3)
// so that in attn, lane l = l16*16+l15 reads its B-fragment as bytes
// [l*16, l*16+16) of the contiguous 1KB segment (keyblk, kk): fully coalesced.
__global__ void normalize_k(const float* __restrict__ x,
                            const float* __restrict__ y,
                            const float* __restrict__ stats,
                            unsigned short* __restrict__ xn,
                            unsigned short* __restrict__ ynP) {
    int idx = (blockIdx.x * 256 + threadIdx.x) * 8;   // grid.x = 1152
    int c = idx & (CH - 1);
    const float* src = blockIdx.y ? y : x;
    const float* st = stats + blockIdx.y * 512;
    float4 v0 = *(const float4*)(src + idx);
    float4 v1 = *(const float4*)(src + idx + 4);
    float f[8] = {v0.x, v0.y, v0.z, v0.w, v1.x, v1.y, v1.z, v1.w};
    bf16x8 o;
#pragma unroll
    for (int j = 0; j < 8; ++j)
        o[j] = (short)f2b((f[j] - st[c + j]) * st[256 + c + j]);
    if (blockIdx.y == 0) {
        *(bf16x8*)(xn + idx) = o;                     // row-major for A-fragments
    } else {
        int key = idx >> 8;
        int dst = (key >> 4) * 4096 + (c >> 5) * 512 + ((c & 31) >> 3) * 128 + (key & 15) * 8;
        *(bf16x8*)(ynP + dst) = o;                    // packed B-fragment layout
    }
}

// ---------------- kernel 4: fused corr -> softmax -> PV: no LDS, no barriers -------
// 72*nsplit blocks (XCD swizzle), 256 thr = 4 waves, wave owns 32 q-rows.
// B-fragments load straight from L2 (per-split keys = 393KB, L2-resident) via
// fully-coalesced 1KB global_load_dwordx4 from the packed ynP layout. Pure
// dataflow loop: compiler pipelines loads across tiles (no barriers to stop it);
// 4 waves/block read the same stream -> L1 reuse.
__launch_bounds__(256, 2)   // VGPR cap 256: proven spill-free regime
__global__ void attn_k(const unsigned short* __restrict__ xn,
                       const unsigned short* __restrict__ ynP,
                       const float* __restrict__ refimg,
                       float* __restrict__ part, int nsplit) {
    int tid = threadIdx.x;
    int lane = tid & 63, wave = tid >> 6;
    int l15 = lane & 15, l16 = lane >> 4;

    // XCD-chunked bijective swizzle (grid % 8 == 0)
    int chunk = gridDim.x >> 3;
    int wg = (blockIdx.x & 7) * chunk + (blockIdx.x >> 3);
    int bx = wg % 72, by = wg / 72;
    int qb = bx * 128 + wave * 32;
    int keys_per_split = HW_N / nsplit;
    int key0 = by * keys_per_split;
    int ntile = keys_per_split / KBLK;

    // A fragments (xn pre-scaled by SCALE2): q = qb + qs*16 + l15, k = kk*32 + l16*8 + j
    bf16x8 a[2][8];
#pragma unroll
    for (int qs = 0; qs < 2; ++qs) {
        const unsigned short* xrow = xn + (size_t)(qb + qs * 16 + l15) * CH + l16 * 8;
#pragma unroll
        for (int kk = 0; kk < 8; ++kk) a[qs][kk] = *(const bf16x8*)(xrow + kk * 32);
    }

    // lane-local state: plain max + raw exp sums (logits bounded, no rescale needed)
    float M[2][4], den[2][4], nA[2][4], nB[2][4];
#pragma unroll
    for (int qs = 0; qs < 2; ++qs)
#pragma unroll
        for (int i = 0; i < 4; ++i) {
            M[qs][i] = -1e30f; den[qs][i] = 0.f; nA[qs][i] = 0.f; nB[qs][i] = 0.f;
        }

    const float* refA = refimg + HW_N;
    const float* refB = refimg + 2 * HW_N;
    // per-lane base into packed layout: lane*16 bytes within each 1KB (keyblk,kk) segment
    const char* ypb = (const char*)ynP + ((size_t)(key0 >> 4) << 13) + lane * 16;

    for (int t = 0; t < ntile; ++t) {
        int kb = key0 + t * KBLK;
        const char* seg = ypb + ((size_t)t << 14);    // 2 keyblocks = 16KB per tile

        // batch all 16 B-fragment loads (compiler issues back-to-back, waits per use)
        bf16x8 b0[8], b1[8];
#pragma unroll
        for (int kk = 0; kk < 8; ++kk) {
            b0[kk] = *(const bf16x8*)(seg + kk * 1024);
            b1[kk] = *(const bf16x8*)(seg + 8192 + kk * 1024);
        }
        // colors for this lane's 2 key columns (L2/L1-resident broadcast loads)
        float va0 = refA[kb + l15],      vb0 = refB[kb + l15];
        float va1 = refA[kb + 16 + l15], vb1 = refB[kb + 16 + l15];

        f32x4 acc0[2], acc1[2];
#pragma unroll
        for (int ct = 0; ct < 2; ++ct) {
            acc0[ct] = (f32x4){0.f, 0.f, 0.f, 0.f};
            acc1[ct] = (f32x4){0.f, 0.f, 0.f, 0.f};
        }
        __builtin_amdgcn_s_setprio(1);
#pragma unroll
        for (int kk = 0; kk < 8; ++kk) {
            acc0[0] = __builtin_amdgcn_mfma_f32_16x16x32_bf16(a[0][kk], b0[kk], acc0[0], 0, 0, 0);
            acc1[0] = __builtin_amdgcn_mfma_f32_16x16x32_bf16(a[1][kk], b0[kk], acc1[0], 0, 0, 0);
            acc0[1] = __builtin_amdgcn_mfma_f32_16x16x32_bf16(a[0][kk], b1[kk], acc0[1], 0, 0, 0);
            acc1[1] = __builtin_amdgcn_mfma_f32_16x16x32_bf16(a[1][kk], b1[kk], acc1[1], 0, 0, 0);
        }
        __builtin_amdgcn_s_setprio(0);

        // acc[ct][i] = scaled corr[q = qb + qs*16 + l16*4 + i][key = kb + ct*16 + l15]
#pragma unroll
        for (int qs = 0; qs < 2; ++qs)
#pragma unroll
            for (int i = 0; i < 4; ++i) {
                float c0 = qs ? acc1[0][i] : acc0[0][i];
                float c1 = qs ? acc1[1][i] : acc0[1][i];
                M[qs][i] = fmaxf(M[qs][i], fmaxf(c0, c1));
                float p0 = exp2f(c0);
                float p1 = exp2f(c1);
                den[qs][i] += p0 + p1;
                nA[qs][i] += p0 * va0 + p1 * va1;
                nB[qs][i] += p0 * vb0 + p1 * vb1;
            }
    }

    // merge lane-local states across the 16 column-lanes: plain sum + max
#pragma unroll
    for (int qs = 0; qs < 2; ++qs)
#pragma unroll
        for (int i = 0; i < 4; ++i) {
#pragma unroll
            for (int off = 1; off < 16; off <<= 1) {
                M[qs][i]   = fmaxf(M[qs][i], __shfl_xor(M[qs][i], off, 64));
                den[qs][i] += __shfl_xor(den[qs][i], off, 64);
                nA[qs][i]  += __shfl_xor(nA[qs][i], off, 64);
                nB[qs][i]  += __shfl_xor(nB[qs][i], off, 64);
            }
        }
    if (l15 == 0) {
#pragma unroll
        for (int qs = 0; qs < 2; ++qs)
#pragma unroll
            for (int i = 0; i < 4; ++i) {
                int q = qb + qs * 16 + l16 * 4 + i;
                float* p = part + ((size_t)by * HW_N + q) * 4;
                p[0] = M[qs][i]; p[1] = den[qs][i]; p[2] = nA[qs][i]; p[3] = nB[qs][i];
            }
    }
}

// ---------------- kernel 5: merge splits, write f32 outputs ------------------------
__global__ void combine_k(const float* __restrict__ part, float* __restrict__ out,
                          int nsplit) {
    int q = blockIdx.x * 256 + threadIdx.x;           // 36 blocks
    float M = -1e30f, den = 0.f, nA = 0.f, nB = 0.f;
    for (int s = 0; s < nsplit; ++s) {
        const float* p = part + ((size_t)s * HW_N + q) * 4;
        M = fmaxf(M, p[0]); den += p[1]; nA += p[2]; nB += p[3];
    }
    out[q]            = nA / den;            // W channel a
    out[HW_N + q]     = nB / den;            // W channel b
    out[2 * HW_N + q] = M * INV_SCALE2;      // confidence = max corr (unscale)
}

extern "C" void kernel_launch(void* const* d_in, const int* in_sizes, int n_in,
                              void* d_out, int out_size, void* d_ws, size_t ws_size,
                              hipStream_t stream) {
    (void)in_sizes; (void)n_in; (void)out_size;
    const float* x   = (const float*)d_in[0];
    const float* y   = (const float*)d_in[1];
    const float* ref = (const float*)d_in[2];
    float* out = (float*)d_out;

    char* ws = (char*)d_ws;
    unsigned short* xn  = (unsigned short*)ws;                    // 4718592 B
    unsigned short* ynP = (unsigned short*)(ws + 4718592);        // 4718592 B (packed)
    float* partA = (float*)ws;                                    // 294912 B (dead before xn written)
    float* stats = (float*)(ws + 2 * 4718592);                    // 4096 B
    float* partS = (float*)(ws + 2 * 4718592 + 4096);             // nsplit*9216*16 B

    // choose key-split count from available workspace (deterministic: ws_size fixed)
    size_t base = 2 * 4718592 + 4096;
    int nsplit = (ws_size >= base + (size_t)12 * HW_N * 16) ? 12 : 6;

    hipLaunchKernelGGL(stats_partial, dim3(72), dim3(256), 0, stream, x, y, partA);
    hipLaunchKernelGGL(stats_final, dim3(1), dim3(256), 0, stream, partA, stats);
    hipLaunchKernelGGL(normalize_k, dim3(1152, 2), dim3(256), 0, stream, x, y, stats, xn, ynP);
    hipLaunchKernelGGL(attn_k, dim3(72 * nsplit), dim3(256), 0, stream, xn, ynP, ref, partS, nsplit);
    hipLaunchKernelGGL(combine_k, dim3(36), dim3(256), 0, stream, partS, out, nsplit);
}